// Round 2
// baseline (867.288 us; speedup 1.0000x reference)
//
#include <hip/hip_runtime.h>
#include <math.h>

#define NV  10
#define H1  64
#define H2  32

// ---------------------------------------------------------------------------
// Kernel 1: adjacency. W = sigmoid(W_logits) with zeroed diagonal; keep only
// entries >= 30th-largest value (top-k mask), write masked W (output #1 tail).
// ---------------------------------------------------------------------------
__global__ void prep_W(const float* __restrict__ Wl, float* __restrict__ Wout) {
    __shared__ float W[100];
    __shared__ float thrv;
    int t = threadIdx.x;
    if (t < 100) {
        int i = t / NV, j = t % NV;
        float w = 1.0f / (1.0f + expf(-Wl[t]));
        if (i == j) w = 0.0f;
        W[t] = w;
    }
    __syncthreads();
    if (t < 100) {
        float v = W[t];
        int cnt = 0;
        #pragma unroll
        for (int k = 0; k < 100; ++k) cnt += (W[k] > v) ? 1 : 0;
        // element with exactly 29 strictly-greater values == 30th largest
        if (cnt == 29) thrv = v;
    }
    __syncthreads();
    if (t < 100) {
        float v = W[t];
        Wout[t] = (v >= thrv) ? v : 0.0f;
    }
}

// ---------------------------------------------------------------------------
// Main kernel: one sample per thread. Weights are wave-uniform reads
// (contiguous, read-only) -> scalar s_load; hot instruction is v_fmac_f32.
// __launch_bounds__(256, 4): 128-VGPR budget so g[64] stays in registers
// (round 1: default 8-wave target -> 56 VGPR + 1.27 GB scratch spill traffic).
// ---------------------------------------------------------------------------
__device__ __forceinline__ float gelu_exact(float x) {
    return 0.5f * x * (1.0f + erff(x * 0.70710678118654752440f));
}

__global__ __launch_bounds__(256, 4) void ncd_main(
    const float* __restrict__ X,    // [B,10]
    const float* __restrict__ Wm,   // [10,10] masked adjacency
    const float* __restrict__ W1,   // [10,64,10]
    const float* __restrict__ b1,   // [10,64]
    const float* __restrict__ W2,   // [10,32,64]
    const float* __restrict__ b2,   // [10,32]
    const float* __restrict__ W3,   // [10,32]
    const float* __restrict__ b3,   // [10]
    float* __restrict__ out,        // [B,10]
    int B)
{
    int b = blockIdx.x * blockDim.x + threadIdx.x;
    if (b >= B) return;

    float x[NV];
    #pragma unroll
    for (int i = 0; i < 5; ++i) {
        float2 v = *reinterpret_cast<const float2*>(X + (size_t)b * NV + 2 * i);
        x[2 * i] = v.x; x[2 * i + 1] = v.y;
    }

    float res[NV];
    #pragma unroll 1
    for (int j = 0; j < NV; ++j) {
        // fold adjacency column j into the input once
        float xj[NV];
        #pragma unroll
        for (int i = 0; i < NV; ++i) xj[i] = x[i] * Wm[i * NV + j];

        // layer 1: g[h] = gelu(b1 + sum_i xj[i] * W1[j,h,i])
        float g[H1];
        #pragma unroll 8
        for (int h = 0; h < H1; ++h) {
            float s = b1[j * H1 + h];
            const float* w = W1 + j * (H1 * NV) + h * NV;
            #pragma unroll
            for (int i = 0; i < NV; ++i) s += xj[i] * w[i];
            g[h] = gelu_exact(s);
        }

        // layer 2 + head: r = b3 + sum_o gelu(b2 + sum_h g[h]*W2[j,o,h]) * W3[j,o]
        float r = b3[j];
        #pragma unroll 4
        for (int o = 0; o < H2; ++o) {
            float s = b2[j * H2 + o];
            const float* w = W2 + j * (H2 * H1) + o * H1;
            #pragma unroll
            for (int h = 0; h < H1; ++h) s += g[h] * w[h];
            r += gelu_exact(s) * W3[j * H2 + o];
        }
        res[j] = r;
    }

    #pragma unroll
    for (int i = 0; i < 5; ++i) {
        float2 v; v.x = res[2 * i]; v.y = res[2 * i + 1];
        *reinterpret_cast<float2*>(out + (size_t)b * NV + 2 * i) = v;
    }
}

extern "C" void kernel_launch(void* const* d_in, const int* in_sizes, int n_in,
                              void* d_out, int out_size, void* d_ws, size_t ws_size,
                              hipStream_t stream) {
    const float* X  = (const float*)d_in[0];
    const float* Wl = (const float*)d_in[1];
    const float* W1 = (const float*)d_in[2];
    const float* b1 = (const float*)d_in[3];
    const float* W2 = (const float*)d_in[4];
    const float* b2 = (const float*)d_in[5];
    const float* W3 = (const float*)d_in[6];
    const float* b3 = (const float*)d_in[7];
    float* out = (float*)d_out;

    int B = in_sizes[0] / NV;                 // 500000
    float* Wout = out + (size_t)B * NV;       // output #2 (the 10x10 W) lives at the tail

    hipLaunchKernelGGL(prep_W, dim3(1), dim3(128), 0, stream, Wl, Wout);

    int grid = (B + 255) / 256;
    hipLaunchKernelGGL(ncd_main, dim3(grid), dim3(256), 0, stream,
                       X, Wout, W1, b1, W2, b2, W3, b3, out, B);
}

// Round 3
// 776.938 us; speedup vs baseline: 1.1163x; 1.1163x over previous
//
#include <hip/hip_runtime.h>
#include <math.h>

#define NV  10
#define H1  64
#define H2  32

// ---------------------------------------------------------------------------
// Kernel 1: adjacency. W = sigmoid(W_logits) with zeroed diagonal; keep only
// entries >= 30th-largest value (top-k mask), write masked W (output #1 tail).
// ---------------------------------------------------------------------------
__global__ void prep_W(const float* __restrict__ Wl, float* __restrict__ Wout) {
    __shared__ float W[100];
    __shared__ float thrv;
    int t = threadIdx.x;
    if (t < 100) {
        int i = t / NV, j = t % NV;
        float w = 1.0f / (1.0f + expf(-Wl[t]));
        if (i == j) w = 0.0f;
        W[t] = w;
    }
    __syncthreads();
    if (t < 100) {
        float v = W[t];
        int cnt = 0;
        #pragma unroll
        for (int k = 0; k < 100; ++k) cnt += (W[k] > v) ? 1 : 0;
        if (cnt == 29) thrv = v;   // exactly 29 strictly greater == 30th largest
    }
    __syncthreads();
    if (t < 100) {
        float v = W[t];
        Wout[t] = (v >= thrv) ? v : 0.0f;
    }
}

// ---------------------------------------------------------------------------
// Main kernel: one sample per thread, layers FUSED so the only per-thread
// state is s2[32] with fully-static indexing (rule #20: any runtime-indexed
// array goes to scratch -- round 1/2 spilled 1.3 GB through g[64]).
// Weight reads are wave-uniform -> s_load; hot instruction is v_fmac_f32.
// ---------------------------------------------------------------------------
__device__ __forceinline__ float gelu_exact(float x) {
    return 0.5f * x * (1.0f + erff(x * 0.70710678118654752440f));
}

__global__ __launch_bounds__(256, 4) void ncd_main(
    const float* __restrict__ X,    // [B,10]
    const float* __restrict__ Wm,   // [10,10] masked adjacency
    const float* __restrict__ W1,   // [10,64,10]
    const float* __restrict__ b1,   // [10,64]
    const float* __restrict__ W2,   // [10,32,64]
    const float* __restrict__ b2,   // [10,32]
    const float* __restrict__ W3,   // [10,32]
    const float* __restrict__ b3,   // [10]
    float* __restrict__ out,        // [B,10]
    int B)
{
    int b = blockIdx.x * blockDim.x + threadIdx.x;
    if (b >= B) return;

    float x[NV];
    #pragma unroll
    for (int i = 0; i < 5; ++i) {
        float2 v = *reinterpret_cast<const float2*>(X + (size_t)b * NV + 2 * i);
        x[2 * i] = v.x; x[2 * i + 1] = v.y;
    }

    float res[NV];
    #pragma unroll 1
    for (int j = 0; j < NV; ++j) {
        // fold adjacency column j into the input once
        float xj[NV];
        #pragma unroll
        for (int i = 0; i < NV; ++i) xj[i] = x[i] * Wm[i * NV + j];

        // layer-2 accumulators (static indices only -> registers)
        float s2[H2];
        #pragma unroll
        for (int o = 0; o < H2; ++o) s2[o] = b2[j * H2 + o];

        const float* w1 = W1 + j * (H1 * NV);
        const float* w2 = W2 + j * (H2 * H1);
        const float* bb1 = b1 + j * H1;

        // stream over hidden units: g = gelu(b1 + xj.w1row); s2[o] += g*W2[o][h]
        #pragma unroll 4
        for (int h = 0; h < H1; ++h) {
            float s = bb1[h];
            const float* w = w1 + h * NV;
            #pragma unroll
            for (int i = 0; i < NV; ++i) s += xj[i] * w[i];
            float g = gelu_exact(s);
            #pragma unroll
            for (int o = 0; o < H2; ++o) s2[o] += g * w2[o * H1 + h];
        }

        // head
        float r = b3[j];
        #pragma unroll
        for (int o = 0; o < H2; ++o) r += gelu_exact(s2[o]) * W3[j * H2 + o];
        res[j] = r;
    }

    #pragma unroll
    for (int i = 0; i < 5; ++i) {
        float2 v; v.x = res[2 * i]; v.y = res[2 * i + 1];
        *reinterpret_cast<float2*>(out + (size_t)b * NV + 2 * i) = v;
    }
}

extern "C" void kernel_launch(void* const* d_in, const int* in_sizes, int n_in,
                              void* d_out, int out_size, void* d_ws, size_t ws_size,
                              hipStream_t stream) {
    const float* X  = (const float*)d_in[0];
    const float* Wl = (const float*)d_in[1];
    const float* W1 = (const float*)d_in[2];
    const float* b1 = (const float*)d_in[3];
    const float* W2 = (const float*)d_in[4];
    const float* b2 = (const float*)d_in[5];
    const float* W3 = (const float*)d_in[6];
    const float* b3 = (const float*)d_in[7];
    float* out = (float*)d_out;

    int B = in_sizes[0] / NV;                 // 500000
    float* Wout = out + (size_t)B * NV;       // output #2 (10x10 W) lives at the tail

    hipLaunchKernelGGL(prep_W, dim3(1), dim3(128), 0, stream, Wl, Wout);

    int grid = (B + 255) / 256;
    hipLaunchKernelGGL(ncd_main, dim3(grid), dim3(256), 0, stream,
                       X, Wout, W1, b1, W2, b2, W3, b3, out, B);
}